// Round 1
// baseline (972.881 us; speedup 1.0000x reference)
//
#include <hip/hip_runtime.h>
#include <math.h>

#define C_DIM 256
#define HW_DIM 1024
#define N_DIM 64
#define M_TOTAL (N_DIM * HW_DIM)   // 65536
#define EPS_F 1e-5f

// ---------------------------------------------------------------------------
// Kernel 1: per-channel mean over m = N*H*W
// grid: 256 (one block per channel), block: 256
__global__ void mean_kernel(const float* __restrict__ X, float* __restrict__ mean) {
    int c = blockIdx.x;
    int t = threadIdx.x;
    float s = 0.f;
    for (int n = 0; n < N_DIM; ++n) {
        const float* p = X + ((size_t)(n * C_DIM + c)) * HW_DIM;
        for (int hw = t; hw < HW_DIM; hw += 256) s += p[hw];
    }
    __shared__ float red[256];
    red[t] = s;
    __syncthreads();
    for (int off = 128; off > 0; off >>= 1) {
        if (t < off) red[t] += red[t + off];
        __syncthreads();
    }
    if (t == 0) mean[c] = red[0] * (1.0f / M_TOTAL);
}

// ---------------------------------------------------------------------------
// Kernel 2: Gram accumulation SigmaAcc += xc_tile @ xc_tile^T  (fp32 atomics)
// grid: (16 tile positions of 64x64, 32 K-splits), block: 256
// Each block covers K range [ks*2048, ks*2048+2048) of m.
#define GKT 32
__global__ void gram_kernel(const float* __restrict__ X, const float* __restrict__ mean,
                            float* __restrict__ SigmaAcc) {
    int tile = blockIdx.x;              // 0..15
    int ci = (tile >> 2) * 64;
    int cj = (tile & 3) * 64;
    int ks = blockIdx.y;                // 0..31
    int t  = threadIdx.x;

    __shared__ float As[64][GKT + 1];
    __shared__ float Bs[64][GKT + 1];
    __shared__ float mA[64], mB[64];
    if (t < 64)       mA[t] = mean[ci + t];
    else if (t < 128) mB[t - 64] = mean[cj + (t - 64)];
    __syncthreads();

    float acc[4][4] = {};
    int ty = t >> 4, tx = t & 15;
    int lkk = t & 31, lr = t >> 5;      // load coords

    for (int stage = 0; stage < 64; ++stage) {
        int j0  = ks * 2048 + stage * GKT;
        int n   = j0 >> 10;
        int hw0 = j0 & 1023;
#pragma unroll
        for (int i = 0; i < 8; ++i) {
            int r = lr + i * 8;
            As[r][lkk] = X[((size_t)(n * C_DIM + ci + r)) * HW_DIM + hw0 + lkk] - mA[r];
            Bs[r][lkk] = X[((size_t)(n * C_DIM + cj + r)) * HW_DIM + hw0 + lkk] - mB[r];
        }
        __syncthreads();
#pragma unroll
        for (int k = 0; k < GKT; ++k) {
            float a[4], b[4];
#pragma unroll
            for (int u = 0; u < 4; ++u) { a[u] = As[ty + 16 * u][k]; b[u] = Bs[tx + 16 * u][k]; }
#pragma unroll
            for (int u = 0; u < 4; ++u)
#pragma unroll
                for (int v = 0; v < 4; ++v) acc[u][v] += a[u] * b[v];
        }
        __syncthreads();
    }
#pragma unroll
    for (int u = 0; u < 4; ++u)
#pragma unroll
        for (int v = 0; v < 4; ++v)
            atomicAdd(&SigmaAcc[(ci + ty + 16 * u) * C_DIM + cj + tx + 16 * v], acc[u][v]);
}

// ---------------------------------------------------------------------------
// Kernel 3: Sigma = acc/m + EPS*I; trace; Sigma_N = Sigma*tr_rec (in place);
//           P = I; scal[0]=tr_rec, scal[1]=sqrt(tr_rec)
// grid: 1, block: 256
__global__ void prep_kernel(float* __restrict__ Sig, float* __restrict__ P,
                            float* __restrict__ scal) {
    int t = threadIdx.x;
    __shared__ float red[256];
    red[t] = Sig[t * C_DIM + t] * (1.0f / M_TOTAL) + EPS_F;
    __syncthreads();
    for (int off = 128; off > 0; off >>= 1) {
        if (t < off) red[t] += red[t + off];
        __syncthreads();
    }
    __shared__ float trr;
    if (t == 0) {
        float tr_rec = 1.0f / red[0];
        trr = tr_rec;
        scal[0] = tr_rec;
        scal[1] = sqrtf(tr_rec);
    }
    __syncthreads();
    float tr_rec = trr;
    for (int idx = t; idx < C_DIM * C_DIM; idx += 256) {
        int r = idx >> 8, cc = idx & 255;
        float v = Sig[idx] * (1.0f / M_TOTAL);
        if (r == cc) v += EPS_F;
        Sig[idx] = v * tr_rec;
        P[idx]   = (r == cc) ? 1.0f : 0.0f;
    }
}

// ---------------------------------------------------------------------------
// 256x256 fp32 matmul. MODE 0: D = A@B ; MODE 1: D = 1.5*D - 0.5*(A@B) ;
// MODE 2: D = (A@B) * scal[1]
// grid: 64 (8x8 tiles of 32x32), block: 256
template <int MODE>
__global__ void mm256_kernel(const float* __restrict__ A, const float* __restrict__ B,
                             float* __restrict__ D, const float* __restrict__ scal) {
    int tile = blockIdx.x;
    int ci = (tile >> 3) * 32, cj = (tile & 7) * 32;
    int t = threadIdx.x;
    int ty = t >> 4, tx = t & 15;
    __shared__ float As[32][33], Bs[32][33];
    float acc[2][2] = {};

    for (int kb = 0; kb < 256; kb += 32) {
        {
            int kk = t & 31, r0 = t >> 5;          // A loads
#pragma unroll
            for (int i = 0; i < 4; ++i)
                As[r0 + 8 * i][kk] = A[(ci + r0 + 8 * i) * C_DIM + kb + kk];
            int cP = t & 31, k2 = t >> 5;          // B loads (transposed store)
#pragma unroll
            for (int i = 0; i < 4; ++i)
                Bs[cP][k2 + 8 * i] = B[(kb + k2 + 8 * i) * C_DIM + cj + cP];
        }
        __syncthreads();
#pragma unroll
        for (int k = 0; k < 32; ++k) {
            float a0 = As[ty][k], a1 = As[ty + 16][k];
            float b0 = Bs[tx][k], b1 = Bs[tx + 16][k];
            acc[0][0] += a0 * b0; acc[0][1] += a0 * b1;
            acc[1][0] += a1 * b0; acc[1][1] += a1 * b1;
        }
        __syncthreads();
    }
#pragma unroll
    for (int u = 0; u < 2; ++u)
#pragma unroll
        for (int v = 0; v < 2; ++v) {
            int r = ci + ty + 16 * u, cc = cj + tx + 16 * v;
            float val = acc[u][v];
            if (MODE == 0)      D[r * C_DIM + cc] = val;
            else if (MODE == 1) D[r * C_DIM + cc] = 1.5f * D[r * C_DIM + cc] - 0.5f * val;
            else                D[r * C_DIM + cc] = val * scal[1];
        }
}

// ---------------------------------------------------------------------------
// Kernel 5: out[n,d,hw] = sum_c M[d,c] * (X[n,c,hw] - mean[c])
// grid: (16 hw-tiles, 4 d-tiles, 64 n), block: 256, 64x64 tile, 4x4 micro
__global__ void out_kernel(const float* __restrict__ X, const float* __restrict__ mean,
                           const float* __restrict__ M, float* __restrict__ out) {
    int hwb = blockIdx.x * 64;
    int db  = blockIdx.y * 64;
    int n   = blockIdx.z;
    int t   = threadIdx.x;
    int ty = t >> 4, tx = t & 15;
    __shared__ float Ms[64][33];   // [d_local][k]
    __shared__ float Xs[64][33];   // [hw_local][k]
    float acc[4][4] = {};

    for (int kb = 0; kb < 256; kb += 32) {
        {
            int kk = t & 31, r0 = t >> 5;          // M loads
#pragma unroll
            for (int i = 0; i < 8; ++i)
                Ms[r0 + 8 * i][kk] = M[(db + r0 + 8 * i) * C_DIM + kb + kk];
            int j = t & 63, k0 = t >> 6;           // X loads
#pragma unroll
            for (int i = 0; i < 8; ++i) {
                int k2 = k0 + 4 * i;
                Xs[j][k2] = X[((size_t)(n * C_DIM + kb + k2)) * HW_DIM + hwb + j] - mean[kb + k2];
            }
        }
        __syncthreads();
#pragma unroll
        for (int k = 0; k < 32; ++k) {
            float a[4], b[4];
#pragma unroll
            for (int u = 0; u < 4; ++u) { a[u] = Ms[ty + 16 * u][k]; b[u] = Xs[tx + 16 * u][k]; }
#pragma unroll
            for (int u = 0; u < 4; ++u)
#pragma unroll
                for (int v = 0; v < 4; ++v) acc[u][v] += a[u] * b[v];
        }
        __syncthreads();
    }
#pragma unroll
    for (int u = 0; u < 4; ++u)
#pragma unroll
        for (int v = 0; v < 4; ++v)
            out[((size_t)(n * C_DIM + db + ty + 16 * u)) * HW_DIM + hwb + tx + 16 * v] = acc[u][v];
}

// ---------------------------------------------------------------------------
extern "C" void kernel_launch(void* const* d_in, const int* in_sizes, int n_in,
                              void* d_out, int out_size, void* d_ws, size_t ws_size,
                              hipStream_t stream) {
    const float* X = (const float*)d_in[0];        // (64,256,32,32)
    const float* R = (const float*)d_in[1];        // (1,256,256)
    float* out = (float*)d_out;
    float* ws  = (float*)d_ws;

    float* mean = ws;                  // 256
    float* scal = ws + 256;            // 16 (tr_rec, sqrt(tr_rec))
    float* Sig  = ws + 512;            // 65536: gram acc -> Sigma_N (in place)
    float* P    = Sig + 65536;         // 65536
    float* T1   = P   + 65536;         // 65536
    float* T2   = T1  + 65536;         // 65536
    float* Mm   = T2  + 65536;         // 65536

    hipMemsetAsync(Sig, 0, C_DIM * C_DIM * sizeof(float), stream);
    mean_kernel<<<256, 256, 0, stream>>>(X, mean);
    gram_kernel<<<dim3(16, 32), 256, 0, stream>>>(X, mean, Sig);
    prep_kernel<<<1, 256, 0, stream>>>(Sig, P, scal);

    for (int it = 0; it < 10; ++it) {
        mm256_kernel<0><<<64, 256, 0, stream>>>(P,  P,   T1, scal);   // T1 = P@P
        mm256_kernel<0><<<64, 256, 0, stream>>>(T1, P,   T2, scal);   // T2 = (P@P)@P
        mm256_kernel<1><<<64, 256, 0, stream>>>(T2, Sig, P,  scal);   // P = 1.5P - 0.5*T2@Sigma_N
    }

    mm256_kernel<2><<<64, 256, 0, stream>>>(R, P, Mm, scal);          // M = (R@P)*sqrt(tr_rec)
    out_kernel<<<dim3(16, 4, 64), 256, 0, stream>>>(X, mean, Mm, out);
}

// Round 2
// 467.689 us; speedup vs baseline: 2.0802x; 2.0802x over previous
//
#include <hip/hip_runtime.h>
#include <math.h>

#define C_DIM 256
#define HW_DIM 1024
#define N_DIM 64
#define M_TOTAL (N_DIM * HW_DIM)   // 65536
#define EPS_F 1e-5f

typedef __attribute__((ext_vector_type(8))) short short8;   // 8 bf16 = 4 VGPR (MFMA A/B frag)
typedef __attribute__((ext_vector_type(4))) float v4f;      // MFMA C/D frag

// fp32 -> bf16 round-to-nearest-even
__device__ __forceinline__ unsigned short f2bf(float x) {
    unsigned u = __float_as_uint(x);
    u = (u + 0x7FFFu + ((u >> 16) & 1u)) >> 16;
    return (unsigned short)u;
}
__device__ __forceinline__ unsigned pack2(float lo, float hi) {
    return (unsigned)f2bf(lo) | ((unsigned)f2bf(hi) << 16);
}

// ---------------------------------------------------------------------------
// Kernel 1: per-channel mean over m = N*H*W (vectorized float4)
// grid: 256 (one block per channel), block: 256
__global__ void mean_kernel(const float* __restrict__ X, float* __restrict__ mean) {
    int c = blockIdx.x;
    int t = threadIdx.x;
    float s = 0.f;
    for (int n = 0; n < N_DIM; ++n) {
        const float4* p = (const float4*)(X + (((size_t)(n * C_DIM + c)) << 10));
        float4 v = p[t];                      // 256 threads x 4 floats = 1024
        s += v.x + v.y + v.z + v.w;
    }
    __shared__ float red[256];
    red[t] = s;
    __syncthreads();
    for (int off = 128; off > 0; off >>= 1) {
        if (t < off) red[t] += red[t + off];
        __syncthreads();
    }
    if (t == 0) mean[c] = red[0] * (1.0f / M_TOTAL);
}

// ---------------------------------------------------------------------------
// Kernel 2: raw Gram G += X_tile @ X_tile^T via bf16 MFMA, fp32 atomics.
// grid: (4 c-tile pairs of 128x128, 64 n), block: 256 (4 waves, each 64x64)
__global__ void gram_mfma(const float* __restrict__ X, float* __restrict__ Sig) {
    int cp = blockIdx.x;                 // 0..3
    int ci = (cp >> 1) * 128, cj = (cp & 1) * 128;
    int n  = blockIdx.y;                 // 0..63  (K-slice = hw of sample n)
    int t  = threadIdx.x;
    int wave = t >> 6, lane = t & 63;
    int wy = wave >> 1, wx = wave & 1;
    int quad = lane >> 4, l16 = lane & 15;

    __shared__ __align__(16) unsigned short As[128 * 40];  // [c_local][k], stride 40 bf16 (80B)
    __shared__ __align__(16) unsigned short Bs[128 * 40];

    v4f acc[4][4] = {};

    const float* Xn = X + ((size_t)n) * C_DIM * HW_DIM;
    int lrow = t >> 3;                   // 0..31
    int lcol = t & 7;                    // float4 within 32-wide k row

    for (int s = 0; s < 32; ++s) {       // 32 stages of BK=32 -> K-slice 1024
        int hw0 = s * 32;
        __syncthreads();                 // previous frag reads done
#pragma unroll
        for (int i = 0; i < 4; ++i) {
            int r = lrow + 32 * i;
            float4 va = *(const float4*)(Xn + ((size_t)(ci + r) << 10) + hw0 + 4 * lcol);
            float4 vb = *(const float4*)(Xn + ((size_t)(cj + r) << 10) + hw0 + 4 * lcol);
            uint2 pa, pb;
            pa.x = pack2(va.x, va.y); pa.y = pack2(va.z, va.w);
            pb.x = pack2(vb.x, vb.y); pb.y = pack2(vb.z, vb.w);
            *(uint2*)(&As[r * 40 + 4 * lcol]) = pa;
            *(uint2*)(&Bs[r * 40 + 4 * lcol]) = pb;
        }
        __syncthreads();

        short8 af[4], bfr[4];
#pragma unroll
        for (int mt = 0; mt < 4; ++mt)
            af[mt] = *(const short8*)(&As[(64 * wy + 16 * mt + l16) * 40 + 8 * quad]);
#pragma unroll
        for (int nt = 0; nt < 4; ++nt)
            bfr[nt] = *(const short8*)(&Bs[(64 * wx + 16 * nt + l16) * 40 + 8 * quad]);
#pragma unroll
        for (int mt = 0; mt < 4; ++mt)
#pragma unroll
            for (int nt = 0; nt < 4; ++nt)
                acc[mt][nt] = __builtin_amdgcn_mfma_f32_16x16x32_bf16(af[mt], bfr[nt], acc[mt][nt], 0, 0, 0);
    }

#pragma unroll
    for (int mt = 0; mt < 4; ++mt)
#pragma unroll
        for (int nt = 0; nt < 4; ++nt)
#pragma unroll
            for (int r = 0; r < 4; ++r) {
                int row = ci + 64 * wy + 16 * mt + quad * 4 + r;
                int col = cj + 64 * wx + 16 * nt + l16;
                atomicAdd(&Sig[row * C_DIM + col], acc[mt][nt][r]);
            }
}

// ---------------------------------------------------------------------------
// Kernel 3: Sigma = G/m - mu*mu^T + EPS*I; trace; Sigma_N = Sigma*tr_rec; P = I
// grid: 1, block: 256
__global__ void prep_kernel(float* __restrict__ Sig, float* __restrict__ P,
                            float* __restrict__ scal, const float* __restrict__ mean) {
    int t = threadIdx.x;
    __shared__ float mu[256];
    mu[t] = mean[t];
    __syncthreads();
    __shared__ float red[256];
    red[t] = Sig[t * C_DIM + t] * (1.0f / M_TOTAL) - mu[t] * mu[t] + EPS_F;
    __syncthreads();
    for (int off = 128; off > 0; off >>= 1) {
        if (t < off) red[t] += red[t + off];
        __syncthreads();
    }
    __shared__ float trr;
    if (t == 0) {
        float tr_rec = 1.0f / red[0];
        trr = tr_rec;
        scal[0] = tr_rec;
        scal[1] = sqrtf(tr_rec);
    }
    __syncthreads();
    float tr_rec = trr;
    for (int idx = t; idx < C_DIM * C_DIM; idx += 256) {
        int r = idx >> 8, cc = idx & 255;
        float v = Sig[idx] * (1.0f / M_TOTAL) - mu[r] * mu[cc];
        if (r == cc) v += EPS_F;
        Sig[idx] = v * tr_rec;
        P[idx]   = (r == cc) ? 1.0f : 0.0f;
    }
}

// ---------------------------------------------------------------------------
// 256x256 fp32 matmul body. MODE 0: D = A@B ; MODE 1: D = 1.5*D - 0.5*(A@B) ;
// MODE 2: D = (A@B) * scal[1].  tile in 0..63 (8x8 of 32x32), block: 256
template <int MODE>
__device__ void mm256_body(const float* __restrict__ A, const float* __restrict__ B,
                           float* __restrict__ D, const float* __restrict__ scal, int tile) {
    int ci = (tile >> 3) * 32, cj = (tile & 7) * 32;
    int t = threadIdx.x;
    int ty = t >> 4, tx = t & 15;
    __shared__ float As[32][33], Bs[32][33];
    float acc[2][2] = {};

    for (int kb = 0; kb < 256; kb += 32) {
        {
            int kk = t & 31, r0 = t >> 5;
#pragma unroll
            for (int i = 0; i < 4; ++i)
                As[r0 + 8 * i][kk] = A[(ci + r0 + 8 * i) * C_DIM + kb + kk];
            int cP = t & 31, k2 = t >> 5;
#pragma unroll
            for (int i = 0; i < 4; ++i)
                Bs[cP][k2 + 8 * i] = B[(kb + k2 + 8 * i) * C_DIM + cj + cP];
        }
        __syncthreads();
#pragma unroll
        for (int k = 0; k < 32; ++k) {
            float a0 = As[ty][k], a1 = As[ty + 16][k];
            float b0 = Bs[tx][k], b1 = Bs[tx + 16][k];
            acc[0][0] += a0 * b0; acc[0][1] += a0 * b1;
            acc[1][0] += a1 * b0; acc[1][1] += a1 * b1;
        }
        __syncthreads();
    }
#pragma unroll
    for (int u = 0; u < 2; ++u)
#pragma unroll
        for (int v = 0; v < 2; ++v) {
            int r = ci + ty + 16 * u, cc = cj + tx + 16 * v;
            float val = acc[u][v];
            if (MODE == 0)      D[r * C_DIM + cc] = val;
            else if (MODE == 1) D[r * C_DIM + cc] = 1.5f * D[r * C_DIM + cc] - 0.5f * val;
            else                D[r * C_DIM + cc] = val * scal[1];
        }
}

// NS level 1: concurrently T1 = P@P (y=0) and T2 = P@Sigma_N (y=1). grid (64,2)
__global__ void ns_level1(const float* __restrict__ P, const float* __restrict__ Sig,
                          float* __restrict__ T1, float* __restrict__ T2) {
    if (blockIdx.y == 0) mm256_body<0>(P, P,   T1, nullptr, blockIdx.x);
    else                 mm256_body<0>(P, Sig, T2, nullptr, blockIdx.x);
}
// NS level 2: P = 1.5P - 0.5*(T1@T2).  ((P@P)@P)@S == (P@P)@(P@S) by associativity.
__global__ void ns_level2(const float* __restrict__ T1, const float* __restrict__ T2,
                          float* __restrict__ P) {
    mm256_body<1>(T1, T2, P, nullptr, blockIdx.x);
}
// Mm = (R @ P) * sqrt(tr_rec). grid 64
__global__ void rot_kernel(const float* __restrict__ R, const float* __restrict__ P,
                           float* __restrict__ Mm, const float* __restrict__ scal) {
    mm256_body<2>(R, P, Mm, scal, blockIdx.x);
}

// ---------------------------------------------------------------------------
// Kernel 6: Mbf = bf16(Mm); moff[d] = dot(Mm[d,:], mean). grid 256, block 64
__global__ void mprep_kernel(const float* __restrict__ Mm, const float* __restrict__ mean,
                             unsigned short* __restrict__ Mbf, float* __restrict__ moff) {
    int d = blockIdx.x, l = threadIdx.x;
    float s = 0.f;
#pragma unroll
    for (int i = 0; i < 4; ++i) {
        int c = l + 64 * i;
        float v = Mm[d * C_DIM + c];
        s += v * mean[c];
        Mbf[d * C_DIM + c] = f2bf(v);
    }
    for (int off = 32; off > 0; off >>= 1) s += __shfl_down(s, off);
    if (l == 0) moff[d] = s;
}

// ---------------------------------------------------------------------------
// Kernel 7: out[n,d,hw] = sum_c Mbf[d,c]*bf16(X[n,c,hw]) - moff[d]  via MFMA
// grid: (8 hw-tiles, 2 d-tiles, 64 n), block 256 (4 waves, each 64x64)
__global__ void out_mfma(const float* __restrict__ X, const unsigned short* __restrict__ Mbf,
                         const float* __restrict__ moff, float* __restrict__ out) {
    int hwb = blockIdx.x * 128;
    int db  = blockIdx.y * 128;
    int n   = blockIdx.z;
    int t = threadIdx.x, wave = t >> 6, lane = t & 63;
    int wy = wave >> 1, wx = wave & 1, quad = lane >> 4, l16 = lane & 15;

    __shared__ __align__(16) unsigned short Asm[128 * 40];  // M tile [d][c], stride 40
    __shared__ __align__(16) unsigned short Bsm[128 * 34];  // X^T tile [hw][c], stride 34 (odd-word)

    v4f acc[4][4] = {};
    const float* Xn = X + ((size_t)n) * C_DIM * HW_DIM;

    for (int kb = 0; kb < 256; kb += 32) {
        __syncthreads();
        // stage A: Mbf[db..+128][kb..+32]
#pragma unroll
        for (int i = 0; i < 2; ++i) {
            int a = t + 256 * i;                 // 0..511 ushort8 chunks
            int row = a >> 2, c8 = a & 3;
            *(uint4*)(&Asm[row * 40 + 8 * c8]) =
                *(const uint4*)(&Mbf[(db + row) * C_DIM + kb + 8 * c8]);
        }
        // stage B transposed: scalar loads (coalesced), scalar LDS writes (2-way max)
#pragma unroll
        for (int i = 0; i < 16; ++i) {
            int idx = t + 256 * i;               // 0..4095 floats
            int hw = idx & 127, crow = idx >> 7; // crow 0..31
            float v = Xn[((size_t)(kb + crow) << 10) + hwb + hw];
            Bsm[hw * 34 + crow] = f2bf(v);
        }
        __syncthreads();

        short8 af[4], bfr[4];
#pragma unroll
        for (int mt = 0; mt < 4; ++mt)
            af[mt] = *(const short8*)(&Asm[(64 * wy + 16 * mt + l16) * 40 + 8 * quad]);
#pragma unroll
        for (int nt = 0; nt < 4; ++nt) {
            union { short8 s; unsigned u[4]; } tmp;
            const unsigned short* base = &Bsm[(64 * wx + 16 * nt + l16) * 34 + 8 * quad];
            tmp.u[0] = *(const unsigned*)(base + 0);
            tmp.u[1] = *(const unsigned*)(base + 2);
            tmp.u[2] = *(const unsigned*)(base + 4);
            tmp.u[3] = *(const unsigned*)(base + 6);
            bfr[nt] = tmp.s;
        }
#pragma unroll
        for (int mt = 0; mt < 4; ++mt)
#pragma unroll
            for (int nt = 0; nt < 4; ++nt)
                acc[mt][nt] = __builtin_amdgcn_mfma_f32_16x16x32_bf16(af[mt], bfr[nt], acc[mt][nt], 0, 0, 0);
    }

#pragma unroll
    for (int mt = 0; mt < 4; ++mt)
#pragma unroll
        for (int r = 0; r < 4; ++r) {
            int d = db + 64 * wy + 16 * mt + quad * 4 + r;
            float off = moff[d];
#pragma unroll
            for (int nt = 0; nt < 4; ++nt) {
                int hw = hwb + 64 * wx + 16 * nt + l16;
                out[((size_t)(n * C_DIM + d) << 10) + hw] = acc[mt][nt][r] - off;
            }
        }
}

// ---------------------------------------------------------------------------
extern "C" void kernel_launch(void* const* d_in, const int* in_sizes, int n_in,
                              void* d_out, int out_size, void* d_ws, size_t ws_size,
                              hipStream_t stream) {
    const float* X = (const float*)d_in[0];        // (64,256,32,32)
    const float* R = (const float*)d_in[1];        // (1,256,256)
    float* out = (float*)d_out;
    float* ws  = (float*)d_ws;

    float* mean = ws;                      // 256
    float* scal = ws + 256;                // 16
    float* Sig  = ws + 512;                // 65536 (raw gram -> Sigma_N in place)
    float* P    = Sig + 65536;             // 65536
    float* T1   = P   + 65536;             // 65536
    float* T2   = T1  + 65536;             // 65536
    float* Mm   = T2  + 65536;             // 65536
    float* moff = Mm  + 65536;             // 256
    unsigned short* Mbf = (unsigned short*)(moff + 256);   // 65536 bf16

    hipMemsetAsync(Sig, 0, C_DIM * C_DIM * sizeof(float), stream);
    mean_kernel<<<256, 256, 0, stream>>>(X, mean);
    gram_mfma<<<dim3(4, 64), 256, 0, stream>>>(X, Sig);
    prep_kernel<<<1, 256, 0, stream>>>(Sig, P, scal, mean);

    for (int it = 0; it < 10; ++it) {
        ns_level1<<<dim3(64, 2), 256, 0, stream>>>(P, Sig, T1, T2);
        ns_level2<<<64, 256, 0, stream>>>(T1, T2, P);
    }

    rot_kernel<<<64, 256, 0, stream>>>(R, P, Mm, scal);
    mprep_kernel<<<256, 64, 0, stream>>>(Mm, mean, Mbf, moff);
    out_mfma<<<dim3(8, 2, 64), 256, 0, stream>>>(X, Mbf, moff, out);
}